// Round 7
// baseline (149.364 us; speedup 1.0000x reference)
//
#include <hip/hip_runtime.h>
#include <hip/hip_bf16.h>

// Problem: B=32, L=512, D=1024, R=128
//   t = batch(16384x1024) @ proj(1024x128)          [bf16 MFMA, fp32 acc]
//   d[b,i,j] = ||t_i||^2 + ||t_j||^2 - 2 t_i.t_j,  clamp >= 0
//
// R7: gemm_t was structure-invariant ~44-56us across 5 designs with all pipes
// idle -> the invariant was the MFMA-native VERTICAL A-access (16 rows x 4KB
// stride, 64-256B per touch) = DRAM row thrash at ~1.5 TB/s. The harness fill
// proves 6.4 TB/s contiguous streaming in this window. So:
//   (1) convert_batch: perfectly-contiguous fp32->bf16 pass (same RNE as the
//       old in-register pack8; numerics unchanged).
//   (2) gemm_t: BK=512, DMA calls = 1KB fully-contiguous row-halves, TWO
//       barriers total, 128 MFMAs between them; B direct from L2 projT.
//   (3) dist_k / transpose_proj unchanged from R6.
// ws: batchB bf16 16384x1024 (33.5MB) | projT bf16 128x1024 | t bf16 16384x128 | sqn f32

typedef __attribute__((ext_vector_type(8))) short bf16x8;
typedef __attribute__((ext_vector_type(4))) float f32x4;

typedef __attribute__((address_space(3))) unsigned lds_u;
typedef __attribute__((address_space(1))) const unsigned gbl_u;

__device__ __forceinline__ void async16(void* lds, const void* g) {
    __builtin_amdgcn_global_load_lds((gbl_u*)(unsigned long long)g,
                                     (lds_u*)(unsigned)(unsigned long long)lds,
                                     16, 0, 0);
}

__device__ __forceinline__ unsigned short f2bf(float f) {
    unsigned u = __float_as_uint(f);
    unsigned r = (u + 0x7fffu + ((u >> 16) & 1u)) >> 16;   // RNE
    return (unsigned short)r;
}
__device__ __forceinline__ float bf2f(unsigned short h) {
    return __uint_as_float(((unsigned)h) << 16);
}
__device__ __forceinline__ bf16x8 pack8(float4 x, float4 y) {
    bf16x8 r;
    r[0] = (short)f2bf(x.x); r[1] = (short)f2bf(x.y);
    r[2] = (short)f2bf(x.z); r[3] = (short)f2bf(x.w);
    r[4] = (short)f2bf(y.x); r[5] = (short)f2bf(y.y);
    r[6] = (short)f2bf(y.z); r[7] = (short)f2bf(y.w);
    return r;
}

// ---------------- kernel A: batch fp32 -> bf16, fully contiguous stream ----------------
// 2048 blocks x 256 threads; each thread 4 iters x 8 elems. Wave reads 2KB
// contiguous per iter (32B/lane), writes 1KB contiguous.
__global__ __launch_bounds__(256) void convert_batch(const float* __restrict__ in,
                                                     unsigned short* __restrict__ outB) {
    size_t g = (size_t)(blockIdx.x * 256 + threadIdx.x) * 8;
    const size_t stride = (size_t)2048 * 256 * 8;           // 4,194,304 elems
#pragma unroll
    for (int i = 0; i < 4; ++i) {
        size_t idx = g + (size_t)i * stride;                // < 16,777,216
        float4 a = *(const float4*)(in + idx);
        float4 b = *(const float4*)(in + idx + 4);
        *(bf16x8*)(outB + idx) = pack8(a, b);
    }
}

// ---------------- kernel 0: proj (1024x128 f32) -> projT (128x1024 bf16) ----------------
__global__ __launch_bounds__(256) void transpose_proj(const float* __restrict__ proj,
                                                      unsigned short* __restrict__ projT) {
    __shared__ unsigned short TsT[128][40];
    const int k0 = blockIdx.x * 32;
    const int t = threadIdx.x;
    const int kl = t >> 3;
    const int seg = t & 7;
    const float* src = proj + (k0 + kl) * 128 + seg * 16;
#pragma unroll
    for (int i = 0; i < 4; ++i) {
        float4 v = *(const float4*)(src + 4 * i);
        int c = seg * 16 + 4 * i;
        TsT[c + 0][kl] = f2bf(v.x);
        TsT[c + 1][kl] = f2bf(v.y);
        TsT[c + 2][kl] = f2bf(v.z);
        TsT[c + 3][kl] = f2bf(v.w);
    }
    __syncthreads();
    const int r = t >> 1, h = t & 1;
#pragma unroll
    for (int i = 0; i < 2; ++i) {
        *(uint4*)(projT + r * 1024 + k0 + h * 16 + 8 * i) =
            *(const uint4*)&TsT[r][h * 16 + 8 * i];
    }
}

// ---------------- kernel 1: t = batchB @ proj  (M=16384, N=128, K=1024, bf16 A) ----------------
// grid 512 (M-tile 32), block 256 = 4 waves (2M x 2N). BK=512: two LDS stages
// of 32KB (32 rows x 1KB), each DMA call stages ONE row-half = 1KB fully
// contiguous (lds = rowblock + lane*16, g = rowstart + lane*16). Two barriers
// total; 128 MFMAs between them. B frags direct from L2-resident projT.
__global__ __launch_bounds__(256) void gemm_t(const unsigned short* __restrict__ batchB,
                                              const unsigned short* __restrict__ projT,
                                              unsigned short* __restrict__ tOut,
                                              float* __restrict__ sqn) {
    __shared__ unsigned char Ls[2][32 * 1024];
    __shared__ float sqpart[2][2][16];

    const int t = threadIdx.x;
    const int wave = t >> 6, lane = t & 63;
    const int wm = wave >> 1, wn = wave & 1;
    const int quad = lane >> 4, l15 = lane & 15;
    const int m0 = blockIdx.x * 32;

    f32x4 acc[4] = {};

    // stage s (0/1): 32 calls (8 per wave), call c stages row (wave*8+c)'s
    // k-half s as 1KB contiguous.
    auto stage = [&](int buf, int s) {
#pragma unroll
        for (int c = 0; c < 8; ++c) {
            int row = wave * 8 + c;
            async16(&Ls[buf][row * 1024 + lane * 16],
                    batchB + (size_t)(m0 + row) * 1024 + s * 512 + lane * 8);
        }
    };

    stage(0, 0);
#pragma unroll
    for (int s = 0; s < 2; ++s) {
        __syncthreads();                          // drain stage s
        if (s == 0) stage(1, 1);
        const unsigned char* Ab = &Ls[s][0];
#pragma unroll
        for (int k = 0; k < 16; ++k) {
            bf16x8 af = *(const bf16x8*)(Ab + (wm * 16 + l15) * 1024 + k * 64 + quad * 16);
            const int kg = s * 512 + k * 32;
#pragma unroll
            for (int fn = 0; fn < 4; ++fn) {
                bf16x8 bfr = *(const bf16x8*)(projT + (wn * 64 + fn * 16 + l15) * 1024
                                              + kg + quad * 8);
                acc[fn] = __builtin_amdgcn_mfma_f32_16x16x32_bf16(af, bfr, acc[fn], 0, 0, 0);
            }
        }
    }

    // epilogue: write t (bf16), row sq-norms from the ROUNDED values
    float p[4] = {0.f, 0.f, 0.f, 0.f};
#pragma unroll
    for (int fn = 0; fn < 4; ++fn) {
        int col = wn * 64 + fn * 16 + l15;
#pragma unroll
        for (int reg = 0; reg < 4; ++reg) {
            int row = m0 + wm * 16 + quad * 4 + reg;
            unsigned short hb = f2bf(acc[fn][reg]);
            tOut[row * 128 + col] = hb;
            float fv = bf2f(hb);
            p[reg] += fv * fv;
        }
    }
#pragma unroll
    for (int off = 1; off < 16; off <<= 1) {
#pragma unroll
        for (int reg = 0; reg < 4; ++reg) p[reg] += __shfl_xor(p[reg], off);
    }
    if (l15 == 0) {
#pragma unroll
        for (int reg = 0; reg < 4; ++reg) sqpart[wm][wn][quad * 4 + reg] = p[reg];
    }
    __syncthreads();
    if (t < 32) {
        int wmi = t >> 4, ridx = t & 15;
        sqn[m0 + wmi * 16 + ridx] = sqpart[wmi][0][ridx] + sqpart[wmi][1][ridx];
    }
}

// ---------------- kernel 2: d[b,i,j] = sq_i + sq_j - 2 * t_i . t_j, clamped ----------------
// grid 512; batch-major swizzle (b = bx & 31). Transposed tile (A=t_j rows per
// wave, B=t_i shared) -> float4 stores. Two-half async volley.
__global__ __launch_bounds__(256) void dist_k(const unsigned short* __restrict__ tMat,
                                              const float* __restrict__ sqn,
                                              float* __restrict__ out) {
    __shared__ unsigned char Ls[64 * 1024];

    const int bx = blockIdx.x;
    const int b = bx & 31, tile = bx >> 5;
    const int it = tile >> 2, jt = tile & 3;
    const int i0 = it * 128, j0 = jt * 128;
    const int t = threadIdx.x;
    const int wave = t >> 6, lane = t & 63;
    const int quad = lane >> 4, l15 = lane & 15;

    const unsigned short* aS = tMat + (b * 512 + j0 + wave * 32 + l15) * 128 + quad * 8;
    const unsigned short* bS = tMat + (b * 512 + i0 + l15) * 128 + quad * 8;

    // ---- half 1: ksi in {0,1} ----
#pragma unroll
    for (int c = 0; c < 4; ++c) {
        int fm = c >> 1, ksi = c & 1;
        async16(&Ls[(wave * 8 + fm * 4 + ksi) * 1024 + lane * 16],
                aS + fm * 16 * 128 + ksi * 32);
    }
#pragma unroll
    for (int c = 0; c < 4; ++c) {
        int idx = wave * 4 + c, fn = idx >> 1, ksi = idx & 1;
        async16(&Ls[32768 + (fn * 4 + ksi) * 1024 + lane * 16],
                bS + fn * 16 * 128 + ksi * 32);
    }

    const float* sqb = sqn + b * 512;
    float sqj_[2][4], sqi_[8];
#pragma unroll
    for (int fm = 0; fm < 2; ++fm)
#pragma unroll
        for (int reg = 0; reg < 4; ++reg)
            sqj_[fm][reg] = sqb[j0 + wave * 32 + fm * 16 + quad * 4 + reg];
#pragma unroll
    for (int fn = 0; fn < 8; ++fn)
        sqi_[fn] = sqb[i0 + fn * 16 + l15];

    __syncthreads();                              // half 1 ready

#pragma unroll
    for (int c = 0; c < 4; ++c) {
        int fm = c >> 1, ksi = 2 + (c & 1);
        async16(&Ls[(wave * 8 + fm * 4 + ksi) * 1024 + lane * 16],
                aS + fm * 16 * 128 + ksi * 32);
    }
#pragma unroll
    for (int c = 0; c < 4; ++c) {
        int idx = wave * 4 + c, fn = idx >> 1, ksi = 2 + (idx & 1);
        async16(&Ls[32768 + (fn * 4 + ksi) * 1024 + lane * 16],
                bS + fn * 16 * 128 + ksi * 32);
    }

    f32x4 acc[2][8] = {};
#pragma unroll
    for (int ksi = 0; ksi < 2; ++ksi) {
        bf16x8 af[2];
#pragma unroll
        for (int fm = 0; fm < 2; ++fm)
            af[fm] = *(const bf16x8*)&Ls[(wave * 8 + fm * 4 + ksi) * 1024 + lane * 16];
#pragma unroll
        for (int fn = 0; fn < 8; ++fn) {
            bf16x8 bfr = *(const bf16x8*)&Ls[32768 + (fn * 4 + ksi) * 1024 + lane * 16];
#pragma unroll
            for (int fm = 0; fm < 2; ++fm)
                acc[fm][fn] = __builtin_amdgcn_mfma_f32_16x16x32_bf16(af[fm], bfr, acc[fm][fn], 0, 0, 0);
        }
    }

    __syncthreads();                              // half 2 ready

#pragma unroll
    for (int ksi = 2; ksi < 4; ++ksi) {
        bf16x8 af[2];
#pragma unroll
        for (int fm = 0; fm < 2; ++fm)
            af[fm] = *(const bf16x8*)&Ls[(wave * 8 + fm * 4 + ksi) * 1024 + lane * 16];
#pragma unroll
        for (int fn = 0; fn < 8; ++fn) {
            bf16x8 bfr = *(const bf16x8*)&Ls[32768 + (fn * 4 + ksi) * 1024 + lane * 16];
#pragma unroll
            for (int fm = 0; fm < 2; ++fm)
                acc[fm][fn] = __builtin_amdgcn_mfma_f32_16x16x32_bf16(af[fm], bfr, acc[fm][fn], 0, 0, 0);
        }
    }

    float* obase = out + (size_t)b * 512 * 512;
#pragma unroll
    for (int fn = 0; fn < 8; ++fn) {
        const int i = i0 + fn * 16 + l15;
        float* orow = obase + (size_t)i * 512 + j0;
        const float si = sqi_[fn];
#pragma unroll
        for (int fm = 0; fm < 2; ++fm) {
            float4 v;
            v.x = fmaxf(si + sqj_[fm][0] - 2.0f * acc[fm][fn][0], 0.0f);
            v.y = fmaxf(si + sqj_[fm][1] - 2.0f * acc[fm][fn][1], 0.0f);
            v.z = fmaxf(si + sqj_[fm][2] - 2.0f * acc[fm][fn][2], 0.0f);
            v.w = fmaxf(si + sqj_[fm][3] - 2.0f * acc[fm][fn][3], 0.0f);
            *(float4*)(orow + wave * 32 + fm * 16 + quad * 4) = v;
        }
    }
}

extern "C" void kernel_launch(void* const* d_in, const int* in_sizes, int n_in,
                              void* d_out, int out_size, void* d_ws, size_t ws_size,
                              hipStream_t stream) {
    (void)in_sizes; (void)n_in; (void)out_size; (void)ws_size;
    const float* batch = (const float*)d_in[0];
    const float* proj  = (const float*)d_in[1];
    float* out = (float*)d_out;

    unsigned short* batchB = (unsigned short*)d_ws;         // 16384*1024 bf16 (33.5MB)
    unsigned short* projT  = batchB + (size_t)16384 * 1024; // 128*1024 bf16
    unsigned short* tMat   = projT + 128 * 1024;            // 16384*128 bf16
    float* sqn = (float*)(tMat + (size_t)16384 * 128);      // 16384 f32

    hipLaunchKernelGGL(convert_batch,  dim3(2048), dim3(256), 0, stream, batch, batchB);
    hipLaunchKernelGGL(transpose_proj, dim3(32),   dim3(256), 0, stream, proj, projT);
    hipLaunchKernelGGL(gemm_t,         dim3(512),  dim3(256), 0, stream, batchB, projT, tMat, sqn);
    hipLaunchKernelGGL(dist_k,         dim3(512),  dim3(256), 0, stream, tMat, sqn, out);
}

// Round 8
// 125.430 us; speedup vs baseline: 1.1908x; 1.1908x over previous
//
#include <hip/hip_runtime.h>
#include <hip/hip_bf16.h>

// Problem: B=32, L=512, D=1024, R=128
//   t = batch(16384x1024) @ proj(1024x128)          [bf16 MFMA, fp32 acc]
//   d[b,i,j] = ||t_i||^2 + ||t_j||^2 - 2 t_i.t_j,  clamp >= 0
//
// R8: revert to the measured-best R4 structure (full-DMA dbuf gemm, M-tile 32,
// BK=64, 1 barrier/step; 3 kernels, no convert pass), upgraded with:
//  - contiguous DMA staging: A calls = 4 rows x 256B, B calls = 8 rows x 128B
//    (burst-friendly vs R4's 16 rows x 64B), fragment reads unchanged b128.
//  - dist_k keeps R6/R7 batch-major XCD swizzle + two-half volley.
// ws: projT bf16 128x1024 | tMat bf16 16384x128 | sqn f32 16384

typedef __attribute__((ext_vector_type(8))) short bf16x8;
typedef __attribute__((ext_vector_type(4))) float f32x4;

typedef __attribute__((address_space(3))) unsigned lds_u;
typedef __attribute__((address_space(1))) const unsigned gbl_u;

__device__ __forceinline__ void async16(void* lds, const void* g) {
    __builtin_amdgcn_global_load_lds((gbl_u*)(unsigned long long)g,
                                     (lds_u*)(unsigned)(unsigned long long)lds,
                                     16, 0, 0);
}

__device__ __forceinline__ unsigned short f2bf(float f) {
    unsigned u = __float_as_uint(f);
    unsigned r = (u + 0x7fffu + ((u >> 16) & 1u)) >> 16;   // RNE
    return (unsigned short)r;
}
__device__ __forceinline__ float bf2f(unsigned short h) {
    return __uint_as_float(((unsigned)h) << 16);
}
__device__ __forceinline__ bf16x8 pack8(float4 x, float4 y) {
    bf16x8 r;
    r[0] = (short)f2bf(x.x); r[1] = (short)f2bf(x.y);
    r[2] = (short)f2bf(x.z); r[3] = (short)f2bf(x.w);
    r[4] = (short)f2bf(y.x); r[5] = (short)f2bf(y.y);
    r[6] = (short)f2bf(y.z); r[7] = (short)f2bf(y.w);
    return r;
}

// ---------------- kernel 0: proj (1024x128 f32) -> projT (128x1024 bf16) ----------------
__global__ __launch_bounds__(256) void transpose_proj(const float* __restrict__ proj,
                                                      unsigned short* __restrict__ projT) {
    __shared__ unsigned short TsT[128][40];
    const int k0 = blockIdx.x * 32;
    const int t = threadIdx.x;
    const int kl = t >> 3;
    const int seg = t & 7;
    const float* src = proj + (k0 + kl) * 128 + seg * 16;
#pragma unroll
    for (int i = 0; i < 4; ++i) {
        float4 v = *(const float4*)(src + 4 * i);
        int c = seg * 16 + 4 * i;
        TsT[c + 0][kl] = f2bf(v.x);
        TsT[c + 1][kl] = f2bf(v.y);
        TsT[c + 2][kl] = f2bf(v.z);
        TsT[c + 3][kl] = f2bf(v.w);
    }
    __syncthreads();
    const int r = t >> 1, h = t & 1;
#pragma unroll
    for (int i = 0; i < 2; ++i) {
        *(uint4*)(projT + r * 1024 + k0 + h * 16 + 8 * i) =
            *(const uint4*)&TsT[r][h * 16 + 8 * i];
    }
}

// ---------------- kernel 1: t = batch @ proj  (M=16384, N=128, K=1024) ----------------
// grid 512 (M-tile 32), block 256 = 4 waves (2M x 2N), BK=64, LDS dbuf 2x24KB.
// Buf layout: A fp32 row-major 32 rows x 256B at [0,8K);
//             B bf16 row-major 128 rows x 128B at [8K,24K).
// Staging (24 calls/block, contiguous segments):
//   A: call ca=wave*2+c (8): rows 4ca..4ca+3, lane l -> row 4ca+(l>>4), byte (l&15)*16
//   B: call cb=wave*4+c (16): rows 8cb..8cb+7, lane l -> row 8cb+(l>>3), byte (l&7)*16
__global__ __launch_bounds__(256) void gemm_t(const float* __restrict__ batch,
                                              const unsigned short* __restrict__ projT,
                                              unsigned short* __restrict__ tOut,
                                              float* __restrict__ sqn) {
    __shared__ unsigned char Ls[2][24 * 1024];
    __shared__ float sqpart[2][2][16];

    const int t = threadIdx.x;
    const int wave = t >> 6, lane = t & 63;
    const int wm = wave >> 1, wn = wave & 1;
    const int quad = lane >> 4, l15 = lane & 15;
    const int m0 = blockIdx.x * 32;

    f32x4 acc[4] = {};

    // staging source pointers (k-offset added per step)
    const float* aSrc[2];
#pragma unroll
    for (int c = 0; c < 2; ++c) {
        int ca = wave * 2 + c;
        aSrc[c] = batch + (size_t)(m0 + ca * 4 + (lane >> 4)) * 1024 + (lane & 15) * 4;
    }
    const unsigned short* bSrc[4];
#pragma unroll
    for (int c = 0; c < 4; ++c) {
        int cb = wave * 4 + c;
        bSrc[c] = projT + (size_t)(cb * 8 + (lane >> 3)) * 1024 + (lane & 7) * 8;
    }

    auto stage = [&](int buf, int kk) {
        unsigned char* base = &Ls[buf][0];
#pragma unroll
        for (int c = 0; c < 2; ++c)
            async16(base + (wave * 2 + c) * 1024 + lane * 16, aSrc[c] + kk);
#pragma unroll
        for (int c = 0; c < 4; ++c)
            async16(base + 8192 + (wave * 4 + c) * 1024 + lane * 16, bSrc[c] + kk);
    };

    stage(0, 0);
#pragma unroll
    for (int s = 0; s < 16; ++s) {
        __syncthreads();                         // drain: buf[s&1] ready
        if (s < 15) stage((s + 1) & 1, (s + 1) * 64);
        const unsigned char* base = &Ls[s & 1][0];
        bf16x8 af[2];
#pragma unroll
        for (int h = 0; h < 2; ++h) {
            const unsigned char* ap = base + (wm * 16 + l15) * 256 + h * 128 + quad * 32;
            float4 f0 = *(const float4*)(ap);
            float4 f1 = *(const float4*)(ap + 16);
            af[h] = pack8(f0, f1);
        }
#pragma unroll
        for (int h = 0; h < 2; ++h)
#pragma unroll
            for (int fn = 0; fn < 4; ++fn) {
                bf16x8 bfr = *(const bf16x8*)(base + 8192 + (wn * 64 + fn * 16 + l15) * 128
                                              + h * 64 + quad * 16);
                acc[fn] = __builtin_amdgcn_mfma_f32_16x16x32_bf16(af[h], bfr, acc[fn], 0, 0, 0);
            }
    }

    // epilogue: write t (bf16), row sq-norms from the ROUNDED values
    float p[4] = {0.f, 0.f, 0.f, 0.f};
#pragma unroll
    for (int fn = 0; fn < 4; ++fn) {
        int col = wn * 64 + fn * 16 + l15;
#pragma unroll
        for (int reg = 0; reg < 4; ++reg) {
            int row = m0 + wm * 16 + quad * 4 + reg;
            unsigned short hb = f2bf(acc[fn][reg]);
            tOut[row * 128 + col] = hb;
            float fv = bf2f(hb);
            p[reg] += fv * fv;
        }
    }
#pragma unroll
    for (int off = 1; off < 16; off <<= 1) {
#pragma unroll
        for (int reg = 0; reg < 4; ++reg) p[reg] += __shfl_xor(p[reg], off);
    }
    if (l15 == 0) {
#pragma unroll
        for (int reg = 0; reg < 4; ++reg) sqpart[wm][wn][quad * 4 + reg] = p[reg];
    }
    __syncthreads();
    if (t < 32) {
        int wmi = t >> 4, ridx = t & 15;
        sqn[m0 + wmi * 16 + ridx] = sqpart[wmi][0][ridx] + sqpart[wmi][1][ridx];
    }
}

// ---------------- kernel 2: d[b,i,j] = sq_i + sq_j - 2 * t_i . t_j, clamped ----------------
// grid 512; batch-major swizzle (b = bx & 31) -> one batch's 16 tiles on one XCD.
// Transposed tile (A=t_j rows per wave, B=t_i shared) -> float4 stores.
// Two-half async volley: compute(half1) overlaps drain(half2).
__global__ __launch_bounds__(256) void dist_k(const unsigned short* __restrict__ tMat,
                                              const float* __restrict__ sqn,
                                              float* __restrict__ out) {
    __shared__ unsigned char Ls[64 * 1024];

    const int bx = blockIdx.x;
    const int b = bx & 31, tile = bx >> 5;
    const int it = tile >> 2, jt = tile & 3;
    const int i0 = it * 128, j0 = jt * 128;
    const int t = threadIdx.x;
    const int wave = t >> 6, lane = t & 63;
    const int quad = lane >> 4, l15 = lane & 15;

    const unsigned short* aS = tMat + (b * 512 + j0 + wave * 32 + l15) * 128 + quad * 8;
    const unsigned short* bS = tMat + (b * 512 + i0 + l15) * 128 + quad * 8;

    // ---- half 1: ksi in {0,1} ----
#pragma unroll
    for (int c = 0; c < 4; ++c) {
        int fm = c >> 1, ksi = c & 1;
        async16(&Ls[(wave * 8 + fm * 4 + ksi) * 1024 + lane * 16],
                aS + fm * 16 * 128 + ksi * 32);
    }
#pragma unroll
    for (int c = 0; c < 4; ++c) {
        int idx = wave * 4 + c, fn = idx >> 1, ksi = idx & 1;
        async16(&Ls[32768 + (fn * 4 + ksi) * 1024 + lane * 16],
                bS + fn * 16 * 128 + ksi * 32);
    }

    const float* sqb = sqn + b * 512;
    float sqj_[2][4], sqi_[8];
#pragma unroll
    for (int fm = 0; fm < 2; ++fm)
#pragma unroll
        for (int reg = 0; reg < 4; ++reg)
            sqj_[fm][reg] = sqb[j0 + wave * 32 + fm * 16 + quad * 4 + reg];
#pragma unroll
    for (int fn = 0; fn < 8; ++fn)
        sqi_[fn] = sqb[i0 + fn * 16 + l15];

    __syncthreads();                              // half 1 ready

#pragma unroll
    for (int c = 0; c < 4; ++c) {
        int fm = c >> 1, ksi = 2 + (c & 1);
        async16(&Ls[(wave * 8 + fm * 4 + ksi) * 1024 + lane * 16],
                aS + fm * 16 * 128 + ksi * 32);
    }
#pragma unroll
    for (int c = 0; c < 4; ++c) {
        int idx = wave * 4 + c, fn = idx >> 1, ksi = 2 + (idx & 1);
        async16(&Ls[32768 + (fn * 4 + ksi) * 1024 + lane * 16],
                bS + fn * 16 * 128 + ksi * 32);
    }

    f32x4 acc[2][8] = {};
#pragma unroll
    for (int ksi = 0; ksi < 2; ++ksi) {
        bf16x8 af[2];
#pragma unroll
        for (int fm = 0; fm < 2; ++fm)
            af[fm] = *(const bf16x8*)&Ls[(wave * 8 + fm * 4 + ksi) * 1024 + lane * 16];
#pragma unroll
        for (int fn = 0; fn < 8; ++fn) {
            bf16x8 bfr = *(const bf16x8*)&Ls[32768 + (fn * 4 + ksi) * 1024 + lane * 16];
#pragma unroll
            for (int fm = 0; fm < 2; ++fm)
                acc[fm][fn] = __builtin_amdgcn_mfma_f32_16x16x32_bf16(af[fm], bfr, acc[fm][fn], 0, 0, 0);
        }
    }

    __syncthreads();                              // half 2 ready (drain overlapped)

#pragma unroll
    for (int ksi = 2; ksi < 4; ++ksi) {
        bf16x8 af[2];
#pragma unroll
        for (int fm = 0; fm < 2; ++fm)
            af[fm] = *(const bf16x8*)&Ls[(wave * 8 + fm * 4 + ksi) * 1024 + lane * 16];
#pragma unroll
        for (int fn = 0; fn < 8; ++fn) {
            bf16x8 bfr = *(const bf16x8*)&Ls[32768 + (fn * 4 + ksi) * 1024 + lane * 16];
#pragma unroll
            for (int fm = 0; fm < 2; ++fm)
                acc[fm][fn] = __builtin_amdgcn_mfma_f32_16x16x32_bf16(af[fm], bfr, acc[fm][fn], 0, 0, 0);
        }
    }

    float* obase = out + (size_t)b * 512 * 512;
#pragma unroll
    for (int fn = 0; fn < 8; ++fn) {
        const int i = i0 + fn * 16 + l15;
        float* orow = obase + (size_t)i * 512 + j0;
        const float si = sqi_[fn];
#pragma unroll
        for (int fm = 0; fm < 2; ++fm) {
            float4 v;
            v.x = fmaxf(si + sqj_[fm][0] - 2.0f * acc[fm][fn][0], 0.0f);
            v.y = fmaxf(si + sqj_[fm][1] - 2.0f * acc[fm][fn][1], 0.0f);
            v.z = fmaxf(si + sqj_[fm][2] - 2.0f * acc[fm][fn][2], 0.0f);
            v.w = fmaxf(si + sqj_[fm][3] - 2.0f * acc[fm][fn][3], 0.0f);
            *(float4*)(orow + wave * 32 + fm * 16 + quad * 4) = v;
        }
    }
}

extern "C" void kernel_launch(void* const* d_in, const int* in_sizes, int n_in,
                              void* d_out, int out_size, void* d_ws, size_t ws_size,
                              hipStream_t stream) {
    (void)in_sizes; (void)n_in; (void)out_size; (void)ws_size;
    const float* batch = (const float*)d_in[0];
    const float* proj  = (const float*)d_in[1];
    float* out = (float*)d_out;

    unsigned short* projT = (unsigned short*)d_ws;          // 128*1024 bf16
    unsigned short* tMat  = projT + 128 * 1024;             // 16384*128 bf16
    float* sqn = (float*)(tMat + (size_t)16384 * 128);      // 16384 f32

    hipLaunchKernelGGL(transpose_proj, dim3(32),  dim3(256), 0, stream, proj, projT);
    hipLaunchKernelGGL(gemm_t,         dim3(512), dim3(256), 0, stream, batch, projT, tMat, sqn);
    hipLaunchKernelGGL(dist_k,         dim3(512), dim3(256), 0, stream, tMat, sqn, out);
}